// Round 7
// baseline (3762.797 us; speedup 1.0000x reference)
//
#include <hip/hip_runtime.h>
#include <stdint.h>
#include <math.h>

#define NB 64
#define NT 512
#define NF 128
#define NH 512
#define NO 128
#define HSTR 520   // LDS A-tile row stride in shorts (512 + 8 pad)

typedef short  s16x8  __attribute__((ext_vector_type(8)));        // 8 bf16
typedef unsigned int u32x4 __attribute__((ext_vector_type(4)));   // asm-safe 16B
typedef float  f32x4  __attribute__((ext_vector_type(4)));        // 16x16 acc
typedef float  f32x16 __attribute__((ext_vector_type(16)));       // 32x32 acc (head)

// ---------------- workspace layout (bytes) ----------------
#define OFF_XBF   ((size_t)0)                      // B*T*F bf16 = 8 MB
#define OFF_WOUT  ((size_t)(8u<<20))               // O*H bf16 = 128 KB
#define OFF_SEQ2  ((size_t)(12u<<20))              // B*T*H bf16 = 32 MB (head input)
#define OFF_RING  ((size_t)(44u<<20))              // 12 groups x 32 slots x 16x512 u32 = 12 MB
#define OFF_PROG  ((size_t)(56u<<20))              // progress lines

#define SMEM_BYTES 88064   // > 80 KB -> exactly 1 WG per CU (160 KB LDS pool)

__device__ __forceinline__ unsigned short f2bf(float f) {
  unsigned int u = __float_as_uint(f);
  u += 0x7fffu + ((u >> 16) & 1u);   // RNE
  return (unsigned short)(u >> 16);
}

__device__ __forceinline__ unsigned int ld_flag(unsigned int* p) {
  return __hip_atomic_load(p, __ATOMIC_RELAXED, __HIP_MEMORY_SCOPE_AGENT);
}
__device__ __forceinline__ unsigned long long ld_u64_agent(const unsigned long long* p) {
  return __hip_atomic_load(p, __ATOMIC_RELAXED, __HIP_MEMORY_SCOPE_AGENT);
}

// poll 4 consecutive slots until min >= tgt (call from lanes 0..3)
__device__ __forceinline__ void poll4(unsigned int* line, int j, unsigned int tgt) {
  unsigned int* p = line + j*4;
  for (;;) {
    unsigned int a = ld_flag(p+0), b = ld_flag(p+1);
    unsigned int c = ld_flag(p+2), d = ld_flag(p+3);
    if (min(min(a,b), min(c,d)) >= tgt) break;
    __builtin_amdgcn_s_sleep(1);
  }
}

__device__ __forceinline__ float sigmoid_f(float x) { return 1.f / (1.f + __expf(-x)); }
__device__ __forceinline__ float tanh_f(float x)    { return 1.f - 2.f / (__expf(2.f*x) + 1.f); }

// ---------------------------------------------------------------------------
// Persistent wavefront-pipelined GRU with epoch-tagged h transport.
// h(t) travels as u32 (epoch<<16 | bf16) in a 32-deep ring: data IS the flag.
// Producer: sc1 stores, no drain, no flag. Consumer: relaxed-agent u64 poll
// loads until every word's epoch matches, then unpack -> LDS -> MFMA.
// 192 WGs (1/CU) = 3 layers x 4 bq x 16 col-slices; 6 waves/WG:
//   phase1: waves0-2 rec r/z/n MFMA(hA); waves3-5 xp r/z/n MFMA(xA)->xpL
//   phase2: wave2 epilogue+ring-store; waves0,1 stage hA(epoch t);
//           waves3,4 stage xA(epoch t+2); wave5 posts progress (backpressure).
// ---------------------------------------------------------------------------
__global__ __launch_bounds__(384, 1)
void gru_persist(const unsigned short* __restrict__ xbf,
                 unsigned short* __restrict__ seq2,
                 unsigned int* __restrict__ ringb,
                 unsigned int* __restrict__ prog,
                 const float* __restrict__ Wih0, const float* __restrict__ Whh0,
                 const float* __restrict__ bih0, const float* __restrict__ bhh0,
                 const float* __restrict__ Wih1, const float* __restrict__ Whh1,
                 const float* __restrict__ bih1, const float* __restrict__ bhh1,
                 const float* __restrict__ Wih2, const float* __restrict__ Whh2,
                 const float* __restrict__ bih2, const float* __restrict__ bhh2)
{
  extern __shared__ char smem[];
  unsigned short* hA = (unsigned short*)smem;                     // 16x520 sh
  unsigned short* xA = (unsigned short*)(smem + 16640);           // 16x520 sh
  float (*xpL)[3][16][33] = (float (*)[3][16][33])(smem + 33280); // 2 slots
  float (*rzL)[16][33]    = (float (*)[16][33])(smem + 45952);
  unsigned int* houtU     = (unsigned int*)(smem + 50176);        // 16x32 u32

  const int tid  = threadIdx.x;
  const int wid  = tid >> 6;
  const int lane = tid & 63;
  const int col  = lane & 15;
  const int quad = lane >> 4;

  const int wg = blockIdx.x;
  const int l  = wg >> 6;
  const int rr = wg & 63;
  const int bq = rr >> 4;
  const int cq = rr & 15;
  const int c0 = cq * 32;
  const int b0 = bq * 16;

  const bool isrec = (wid < 3);
  const int  g     = isrec ? wid : wid - 3;

  const float* Whh = (l==0)?Whh0:(l==1)?Whh1:Whh2;
  const float* Wih = (l==0)?Wih0:(l==1)?Wih1:Wih2;
  const float* bhh = (l==0)?bhh0:(l==1)?bhh1:bhh2;
  const float* bih = (l==0)?bih0:(l==1)?bih1:bih2;

  const float* Wsrc = isrec ? Whh : Wih;
  const int K   = isrec ? NH : ((l==0) ? NF : NH);
  const int KT  = K >> 5;
  const int KTx = (l==0) ? 4 : 16;

  // ring: per (l,bq): 32 slots x (16 rows x 512 cols) u32
  unsigned int* ringw = ringb + (size_t)(l*4 + bq) * 262144;
  const unsigned int* ringr = (l > 0) ? ringb + (size_t)((l-1)*4 + bq) * 262144 : ringb;

  // ---- preload weight slice into regs (B-frag order), bf16 ----
  s16x8 wr0[16], wr1[16];
  #pragma unroll
  for (int kt = 0; kt < 16; ++kt) {
    if (kt < KT) {
      const float* s0 = Wsrc + (size_t)(g*NH + c0 +      col) * K + kt*32 + quad*8;
      const float* s1 = Wsrc + (size_t)(g*NH + c0 + 16 + col) * K + kt*32 + quad*8;
      s16x8 w0, w1;
      #pragma unroll
      for (int j = 0; j < 8; ++j) { w0[j] = (short)f2bf(s0[j]); w1[j] = (short)f2bf(s1[j]); }
      wr0[kt] = w0; wr1[kt] = w1;
    } else { wr0[kt] = (s16x8)0; wr1[kt] = (s16x8)0; }
  }
  const float* bb = isrec ? bhh : bih;
  const float bias0 = bb[g*NH + c0 +      col];
  const float bias1 = bb[g*NH + c0 + 16 + col];

  // stage one 8-row half of a ring slot into LDS (bf16), polling epochs.
  // lane mapping: 8 lanes/row, adjacent lanes -> adjacent u64 (64B/line-group).
  auto stage_ring = [&](unsigned short* dstL, const unsigned int* slotbase,
                        unsigned int tag, int half) {
    const int r  = (half << 3) + (lane >> 3);
    const int sc = lane & 7;
    const unsigned long long* src = (const unsigned long long*)(slotbase + (size_t)r*NH);
    unsigned long long v[32];
    #pragma unroll
    for (int i = 0; i < 32; ++i) v[i] = ld_u64_agent(src + i*8 + sc);
    const unsigned long long want =
        ((unsigned long long)tag << 48) | ((unsigned long long)tag << 16);
    for (;;) {
      bool bad = false;
      #pragma unroll
      for (int i = 0; i < 32; ++i) {
        if (((v[i] ^ want) & 0xFFFF0000FFFF0000ull) != 0ull) {
          v[i] = ld_u64_agent(src + i*8 + sc);
          bad = true;
        }
      }
      if (!bad) break;
      __builtin_amdgcn_s_sleep(1);
    }
    #pragma unroll
    for (int i = 0; i < 32; ++i) {
      unsigned int pk = (unsigned int)(v[i] & 0xFFFFu) | ((unsigned int)(v[i] >> 32) << 16);
      *(unsigned int*)&dstL[(size_t)r*HSTR + i*16 + sc*2] = pk;
    }
  };
  // stage xbf tile (layer 0 input, static, plain cached loads)
  auto stage_xbf = [&](unsigned short* dstL, int step, int half) {
    const int r  = (half << 3) + (lane >> 3);
    const int sc = lane & 7;
    const unsigned short* src = xbf + ((size_t)(b0 + r)*NT + step)*NF;
    #pragma unroll
    for (int j = 0; j < 2; ++j) {
      s16x8 w = *(const s16x8*)(src + (j*8 + sc)*8);
      *(s16x8*)&dstL[(size_t)r*HSTR + (j*8 + sc)*8] = w;
    }
  };

  // ---- prologue: xA(epoch0) -> xp(0) -> xA(epoch1) ----
  if (wid == 3 || wid == 4) {
    if (l == 0) stage_xbf(xA, 0, wid - 3);
    else        stage_ring(xA, ringr, 0u, wid - 3);
  }
  __syncthreads();
  if (!isrec) {
    f32x4 a0 = {0.f,0.f,0.f,0.f}, a1 = {0.f,0.f,0.f,0.f};
    #pragma unroll
    for (int kt = 0; kt < 16; ++kt) if (kt < KTx) {
      s16x8 a = *(const s16x8*)&xA[col*HSTR + kt*32 + quad*8];
      a0 = __builtin_amdgcn_mfma_f32_16x16x32_bf16(a, wr0[kt], a0, 0, 0, 0);
      a1 = __builtin_amdgcn_mfma_f32_16x16x32_bf16(a, wr1[kt], a1, 0, 0, 0);
    }
    #pragma unroll
    for (int i = 0; i < 4; ++i) {
      int row = quad*4 + i;
      xpL[0][g][row][col]      = a0[i] + bias0;
      xpL[0][g][row][col + 16] = a1[i] + bias1;
    }
  }
  __syncthreads();
  if (wid == 3 || wid == 4) {
    if (l == 0) stage_xbf(xA, 1, wid - 3);
    else        stage_ring(xA, ringr + (size_t)1*8192, 1u, wid - 3);
  }
  __syncthreads();

  float hp0[4] = {0.f,0.f,0.f,0.f}, hp1[4] = {0.f,0.f,0.f,0.f};  // n-wave h state

  for (int t = 0; t < NT; ++t) {
    const int slot  = t & 1;
    const int nslot = slot ^ 1;

    f32x4 a0 = {0.f,0.f,0.f,0.f}, a1 = {0.f,0.f,0.f,0.f};

    // ---------------- phase 1: pure LDS -> MFMA ----------------
    if (isrec) {
      if (t > 0) {
        #pragma unroll
        for (int kt = 0; kt < 16; ++kt) {
          s16x8 a = *(const s16x8*)&hA[col*HSTR + kt*32 + quad*8];
          a0 = __builtin_amdgcn_mfma_f32_16x16x32_bf16(a, wr0[kt], a0, 0, 0, 0);
          a1 = __builtin_amdgcn_mfma_f32_16x16x32_bf16(a, wr1[kt], a1, 0, 0, 0);
        }
      }
      if (g < 2) {
        #pragma unroll
        for (int i = 0; i < 4; ++i) {
          int row = quad*4 + i;
          float p0 = a0[i] + xpL[slot][g][row][col]      + bias0;
          float p1 = a1[i] + xpL[slot][g][row][col + 16] + bias1;
          rzL[g][row][col]      = sigmoid_f(p0);
          rzL[g][row][col + 16] = sigmoid_f(p1);
        }
      } else {
        #pragma unroll
        for (int i = 0; i < 4; ++i) { a0[i] += bias0; a1[i] += bias1; }
      }
    } else if (t + 1 < NT) {   // xp(t+1) from xA -> xpL[nslot]
      #pragma unroll
      for (int kt = 0; kt < 16; ++kt) if (kt < KTx) {
        s16x8 a = *(const s16x8*)&xA[col*HSTR + kt*32 + quad*8];
        a0 = __builtin_amdgcn_mfma_f32_16x16x32_bf16(a, wr0[kt], a0, 0, 0, 0);
        a1 = __builtin_amdgcn_mfma_f32_16x16x32_bf16(a, wr1[kt], a1, 0, 0, 0);
      }
      #pragma unroll
      for (int i = 0; i < 4; ++i) {
        int row = quad*4 + i;
        xpL[nslot][g][row][col]      = a0[i] + bias0;
        xpL[nslot][g][row][col + 16] = a1[i] + bias1;
      }
    }
    __syncthreads();   // B1

    // ---------------- phase 2 ----------------
    if (wid == 2) {
      // backpressure: ring reuse safe if next layer within 18 steps.
      // overwrites in [t,t+16) touch epochs <= t-17; posted p covers reads
      // of epochs <= p+2  ->  need p >= t-19.
      if (l < 2 && (t & 15) == 0 && t >= 20 && lane < 4)
        poll4(prog + (size_t)((l+1)*4 + bq)*16, lane, (unsigned)(t - 19));
      const unsigned tg = (unsigned)t << 16;
      #pragma unroll
      for (int i = 0; i < 4; ++i) {
        int row = quad*4 + i;
        float xn0 = xpL[slot][2][row][col];
        float xn1 = xpL[slot][2][row][col + 16];
        float rt0 = rzL[0][row][col],      rt1 = rzL[0][row][col + 16];
        float zt0 = rzL[1][row][col],      zt1 = rzL[1][row][col + 16];
        float nv0 = tanh_f(xn0 + rt0 * a0[i]);
        float nv1 = tanh_f(xn1 + rt1 * a1[i]);
        float h0 = (1.f - zt0)*nv0 + zt0*hp0[i];
        float h1 = (1.f - zt1)*nv1 + zt1*hp1[i];
        hp0[i] = h0; hp1[i] = h1;
        houtU[row*32 + col]      = tg | f2bf(h0);
        houtU[row*32 + col + 16] = tg | f2bf(h1);
      }
      asm volatile("s_waitcnt lgkmcnt(0)" ::: "memory");
      {
        int srow = lane >> 2, sch = lane & 3;
        u32x4 w0 = *(const u32x4*)&houtU[srow*32 + sch*8];
        u32x4 w1 = *(const u32x4*)&houtU[srow*32 + sch*8 + 4];
        unsigned int* p = ringw + (size_t)(t & 31)*8192 + (size_t)srow*NH + c0 + sch*8;
        asm volatile("global_store_dwordx4 %0, %1, off sc0 sc1" :: "v"(p),   "v"(w0) : "memory");
        asm volatile("global_store_dwordx4 %0, %1, off sc0 sc1" :: "v"(p+4), "v"(w1) : "memory");
        if (l == 2) {   // plain bf16 copy for the head (cross-kernel visible)
          s16x8 hb;
          hb[0]=(short)w0[0]; hb[1]=(short)w0[1]; hb[2]=(short)w0[2]; hb[3]=(short)w0[3];
          hb[4]=(short)w1[0]; hb[5]=(short)w1[1]; hb[6]=(short)w1[2]; hb[7]=(short)w1[3];
          *(s16x8*)&seq2[((size_t)(b0+srow)*NT + t)*NH + c0 + sch*8] = hb;
        }
      }
      // no vmcnt, no flag: consumers poll the tagged data itself
    } else if (wid < 2) {                 // stage hA = h(t) for step t+1
      if (t + 1 < NT)
        stage_ring(hA, ringw + (size_t)(t & 31)*8192, (unsigned)t, wid);
    } else if (wid == 3 || wid == 4) {    // stage xA = src(t+2)
      if (t + 2 < NT) {
        if (l == 0) stage_xbf(xA, t + 2, wid - 3);
        else        stage_ring(xA, ringr + (size_t)((t+2) & 31)*8192, (unsigned)(t+2), wid - 3);
      }
    } else {                              // wave 5: progress post (backpressure)
      if (l > 0 && lane == 0)
        __hip_atomic_store(prog + (size_t)(l*4 + bq)*16 + cq,
                           (t ? (unsigned)(t - 1) : 0u),
                           __ATOMIC_RELAXED, __HIP_MEMORY_SCOPE_AGENT);
    }
    __syncthreads();   // B2
  }
}

// ---------------- head GEMM: out[bt][o] = seq2[bt][:] . Wout[o][:] + bout ----
__global__ __launch_bounds__(256)
void head_gemm(const unsigned short* __restrict__ seq2,
               const unsigned short* __restrict__ woutb,
               const float* __restrict__ bout,
               float* __restrict__ out)
{
  int tid = threadIdx.x;
  int wv = tid >> 6, lane = tid & 63;
  int col = lane & 31, khi = lane >> 5;
  int id = blockIdx.x*4 + wv;
  int mt = id >> 2, nt = id & 3;
  int m0 = mt*32, n0 = nt*32;
  const unsigned short* arow = seq2  + (size_t)(m0 + col)*NH + (khi << 3);
  const unsigned short* brow = woutb + (size_t)(n0 + col)*NH + (khi << 3);
  f32x16 acc;
  #pragma unroll
  for (int i = 0; i < 16; ++i) acc[i] = 0.f;
  #pragma unroll 8
  for (int kt = 0; kt < 32; ++kt) {
    s16x8 a = *(const s16x8*)(arow + kt*16);
    s16x8 b = *(const s16x8*)(brow + kt*16);
    acc = __builtin_amdgcn_mfma_f32_32x32x16_bf16(a, b, acc, 0, 0, 0);
  }
  float bo = bout[n0 + col];
  #pragma unroll
  for (int r = 0; r < 16; ++r) {
    int row = (r & 3) + ((r >> 2) << 3) + (khi << 2);
    out[(size_t)(m0 + row)*NO + n0 + col] = acc[r] + bo;
  }
}

__global__ void cast_f32_bf16(const float* __restrict__ src,
                              unsigned short* __restrict__ dst, int n) {
  int i = blockIdx.x*blockDim.x + threadIdx.x;
  int stride = gridDim.x*blockDim.x;
  for (; i < n; i += stride) dst[i] = f2bf(src[i]);
}

extern "C" void kernel_launch(void* const* d_in, const int* in_sizes, int n_in,
                              void* d_out, int out_size, void* d_ws, size_t ws_size,
                              hipStream_t stream) {
  (void)in_sizes; (void)n_in; (void)out_size; (void)ws_size;
  const float* x    = (const float*)d_in[0];
  const float* Wih0 = (const float*)d_in[1];
  const float* Whh0 = (const float*)d_in[2];
  const float* bih0 = (const float*)d_in[3];
  const float* bhh0 = (const float*)d_in[4];
  const float* Wih1 = (const float*)d_in[5];
  const float* Whh1 = (const float*)d_in[6];
  const float* bih1 = (const float*)d_in[7];
  const float* bhh1 = (const float*)d_in[8];
  const float* Wih2 = (const float*)d_in[9];
  const float* Whh2 = (const float*)d_in[10];
  const float* bih2 = (const float*)d_in[11];
  const float* bhh2 = (const float*)d_in[12];
  const float* Wout = (const float*)d_in[13];
  const float* bout = (const float*)d_in[14];

  char* ws = (char*)d_ws;
  unsigned short* xbf  = (unsigned short*)(ws + OFF_XBF);
  unsigned short* wob  = (unsigned short*)(ws + OFF_WOUT);
  unsigned short* seq2 = (unsigned short*)(ws + OFF_SEQ2);
  unsigned int*   ring = (unsigned int*)(ws + OFF_RING);
  unsigned int*   prg  = (unsigned int*)(ws + OFF_PROG);

  // allow >64KB dynamic LDS (idempotent, capture-safe)
  (void)hipFuncSetAttribute((const void*)gru_persist,
                            hipFuncAttributeMaxDynamicSharedMemorySize, 160*1024);

  (void)hipMemsetAsync(ws + OFF_PROG, 0, 4096, stream);
  cast_f32_bf16<<<512, 256, 0, stream>>>(x, xbf, NB*NT*NF);
  cast_f32_bf16<<<64, 256, 0, stream>>>(Wout, wob, NO*NH);
  gru_persist<<<192, 384, SMEM_BYTES, stream>>>(xbf, seq2, ring, prg,
      Wih0, Whh0, bih0, bhh0, Wih1, Whh1, bih1, bhh1, Wih2, Whh2, bih2, bhh2);
  head_gemm<<<1024, 256, 0, stream>>>(seq2, wob, bout, (float*)d_out);
}